// Round 1
// 1091.577 us; speedup vs baseline: 1.9828x; 1.9828x over previous
//
#include <hip/hip_runtime.h>
#include <stdint.h>

// SelfRNN: 4-layer tanh RNN, SEQ=256, B=64, H=512.
// R3: fence-free sync. The per-step agent fences (buffer_wbl2 + buffer_inv,
// 128 WGs x 256 steps) were serializing at the 8 per-XCD L2s. Replaced by
// access-level coherence: activations move via relaxed agent-scope atomic
// stores/loads (sc-flagged, cross-XCD coherent, same mechanism as the flags).
// Release ordering = the vmcnt(0) drain __syncthreads already performs.
// Also: GN 8->4 (fan-in and coherent volume halved), TPB 512 (8 waves),
// phase-split waits (stage layer-feed half while own-layer h edge settles),
// f32 result stores deferred past the flag increment (drain off critical path).

#define SEQ 256
#define BB  64
#define HH  512
#define NL  4
#define GM  4          // batch groups of 16 rows
#define GN  4          // column groups of 128 cols (16 per wave, 8 waves)
#define TPB 512        // threads per workgroup (8 waves) for rnn_main
#define WGT 256        // threads for rnn_prep
#define LDS_STRIDE 1032  // 1024 + 8 shorts pad (16B) -> conflict-benign b128 reads
#define FLAG_STRIDE 16   // 16 ints = 64B per flag -> no false sharing
#define FIDX(t,i,m) ((((t)*NL + (i))*GM + (m)) * FLAG_STRIDE)

typedef __attribute__((ext_vector_type(8))) short bf16x8;
typedef __attribute__((ext_vector_type(4))) float f32x4;

__device__ inline short f2bf(float f){
  uint32_t u = __builtin_bit_cast(uint32_t, f);
  u += 0x7fffu + ((u >> 16) & 1u);   // round-to-nearest-even
  return (short)(u >> 16);
}

__device__ inline float fast_tanh(float xv){
  xv = fminf(15.0f, fmaxf(-15.0f, xv));
  float e = __expf(2.0f * xv);
  return (e - 1.0f) / (e + 1.0f);
}

// Relaxed agent-scope poll; no fence needed afterward since all communicated
// data is itself accessed with agent-coherent ops.
__device__ inline void spin_ge(int* f, int target){
  int it = 0;
  while (__hip_atomic_load(f, __ATOMIC_RELAXED, __HIP_MEMORY_SCOPE_AGENT) < target){
    __builtin_amdgcn_s_sleep(1);
    if (++it > (1 << 24)) break;   // bailout: wrong-but-terminating beats hang
  }
}

// Agent-coherent 16B load as 2x u64 (device-coherent path; no fence needed).
__device__ inline bf16x8 load_cc16(const short* p){
  const uint64_t* q = (const uint64_t*)p;
  union { uint64_t u[2]; bf16x8 v; } r;
  r.u[0] = __hip_atomic_load(q + 0, __ATOMIC_RELAXED, __HIP_MEMORY_SCOPE_AGENT);
  r.u[1] = __hip_atomic_load(q + 1, __ATOMIC_RELAXED, __HIP_MEMORY_SCOPE_AGENT);
  return r.v;
}

// Fallback path (usews==0): agent-coherent load of 8 f32 -> bf16x8.
__device__ inline bf16x8 load_cc_f32x8(const float* p){
  const uint64_t* q = (const uint64_t*)p;
  bf16x8 s;
  #pragma unroll
  for (int z = 0; z < 4; ++z){
    uint64_t u = __hip_atomic_load(q + z, __ATOMIC_RELAXED, __HIP_MEMORY_SCOPE_AGENT);
    s[2*z + 0] = f2bf(__builtin_bit_cast(float, (uint32_t)(u & 0xffffffffu)));
    s[2*z + 1] = f2bf(__builtin_bit_cast(float, (uint32_t)(u >> 32)));
  }
  return s;
}

// Zero sync flags (d_ws is re-poisoned each call) and convert x to bf16 shadow.
// Flags zeroed with agent-coherent stores so the sc-flagged polls in rnn_main
// can never observe a stale poisoned line.
__global__ void rnn_prep(const float* __restrict__ x, short* __restrict__ xbf,
                         int* __restrict__ flags, int usews){
  int bid = blockIdx.x, tid = threadIdx.x;
  if (bid == 0){
    for (int k = tid; k < SEQ*NL*GM*FLAG_STRIDE; k += WGT)
      __hip_atomic_store(&flags[k], 0, __ATOMIC_RELAXED, __HIP_MEMORY_SCOPE_AGENT);
  }
  if (usews && bid >= 1){
    long base = ((long)(bid - 1) * WGT + tid) * 8;  // 4096 blocks cover 8.39M elems
    f32x4 a = *(const f32x4*)(x + base);
    f32x4 b = *(const f32x4*)(x + base + 4);
    bf16x8 s;
    s[0]=f2bf(a[0]); s[1]=f2bf(a[1]); s[2]=f2bf(a[2]); s[3]=f2bf(a[3]);
    s[4]=f2bf(b[0]); s[5]=f2bf(b[1]); s[6]=f2bf(b[2]); s[7]=f2bf(b[3]);
    *(bf16x8*)(xbf + base) = s;
  }
}

__global__ __launch_bounds__(TPB, 2)   // 8 waves = 2/SIMD -> VGPR cap 256
void rnn_main(const float* __restrict__ x,
              const float* __restrict__ w_ih, const float* __restrict__ b_ih,
              const float* __restrict__ w_hh, const float* __restrict__ b_hh,
              float* __restrict__ out,
              short* __restrict__ xbf, short* __restrict__ actbf,
              int* __restrict__ flags, int usews)
{
  const int tid  = threadIdx.x;
  const int wv   = tid >> 6;             // 0..7
  const int lane = tid & 63;
  const int bid  = blockIdx.x;           // grid = NL*GM*GN = 64
  const int n = bid >> 4;                // 0..3 column group
  const int i = (bid >> 2) & 3;          // layer
  const int m = bid & 3;                 // batch group

  const int l15  = lane & 15;
  const int lq   = lane >> 4;            // quarter-wave 0..3
  const int jcol = n*128 + wv*16 + l15;  // this wave's 16 output cols
  const int ksub = lq * 8;

  __shared__ short lA[16 * LDS_STRIDE];  // A tile [16 rows][1024 k] bf16, padded

  // ---- persistent weight fragments: B-operand, [16 cols x 1024 k] per wave ----
  bf16x8 wf[32];
  {
    const float* wih = w_ih + (long)i*HH*HH + (long)jcol*HH;
    const float* whh = w_hh + (long)i*HH*HH + (long)jcol*HH;
    #pragma unroll
    for (int kk = 0; kk < 16; ++kk){
      const float* p = wih + kk*32 + ksub;
      f32x4 a = *(const f32x4*)p, b = *(const f32x4*)(p + 4);
      bf16x8 s;
      s[0]=f2bf(a[0]); s[1]=f2bf(a[1]); s[2]=f2bf(a[2]); s[3]=f2bf(a[3]);
      s[4]=f2bf(b[0]); s[5]=f2bf(b[1]); s[6]=f2bf(b[2]); s[7]=f2bf(b[3]);
      wf[kk] = s;
      const float* q = whh + kk*32 + ksub;
      f32x4 c = *(const f32x4*)q, d = *(const f32x4*)(q + 4);
      bf16x8 u;
      u[0]=f2bf(c[0]); u[1]=f2bf(c[1]); u[2]=f2bf(c[2]); u[3]=f2bf(c[3]);
      u[4]=f2bf(d[0]); u[5]=f2bf(d[1]); u[6]=f2bf(d[2]); u[7]=f2bf(d[3]);
      wf[kk + 16] = u;
    }
  }
  const float bsum = b_ih[(long)i*HH + jcol] + b_hh[(long)i*HH + jcol];

  float* states = out + (long)SEQ*BB*HH;   // all_states region: [(t*4+i)][b][h]
  const int bg0 = m * 16;

  for (int t = 0; t < SEQ; ++t){
    // ---- phase 1: layer feed (has pipeline slack) — wait + stage inp half ----
    if (i > 0){
      if (tid == 0) spin_ge(&flags[FIDX(t, i-1, m)], GN);
      __syncthreads();
    }
    #pragma unroll
    for (int c = 0; c < 2; ++c){
      int chunk = c*TPB + tid;            // 1024 chunks of 8 elems = 16 rows x 512
      int row   = chunk >> 6;
      int col0  = (chunk & 63) * 8;
      int bg    = bg0 + row;
      bf16x8 s;
      if (usews){
        if (i == 0) s = *(const bf16x8*)(xbf + ((long)t*BB + bg)*HH + col0);
        else        s = load_cc16(actbf + ((long)(t*NL + (i-1))*BB + bg)*HH + col0);
      } else {
        if (i == 0){
          const float* src = x + ((long)t*BB + bg)*HH + col0;
          f32x4 a = *(const f32x4*)src, b2 = *(const f32x4*)(src + 4);
          s[0]=f2bf(a[0]); s[1]=f2bf(a[1]); s[2]=f2bf(a[2]); s[3]=f2bf(a[3]);
          s[4]=f2bf(b2[0]); s[5]=f2bf(b2[1]); s[6]=f2bf(b2[2]); s[7]=f2bf(b2[3]);
        } else {
          s = load_cc_f32x8(states + ((long)(t*NL + (i-1))*BB + bg)*HH + col0);
        }
      }
      *(bf16x8*)(lA + row*LDS_STRIDE + col0) = s;
    }

    // ---- phase 2: recurrence edge (tight) — wait + stage h half ----
    if (t > 0){
      if (tid == 0) spin_ge(&flags[FIDX(t-1, i, m)], GN);
      __syncthreads();
      #pragma unroll
      for (int c = 0; c < 2; ++c){
        int chunk = c*TPB + tid;
        int row   = chunk >> 6;
        int col0  = (chunk & 63) * 8;
        int bg    = bg0 + row;
        bf16x8 s;
        if (usews) s = load_cc16(actbf + ((long)((t-1)*NL + i)*BB + bg)*HH + col0);
        else       s = load_cc_f32x8(states + ((long)((t-1)*NL + i)*BB + bg)*HH + col0);
        *(bf16x8*)(lA + row*LDS_STRIDE + 512 + col0) = s;
      }
    }
    __syncthreads();

    // ---- MFMA: out[16 rows x 16 cols]/wave, K=1024 (512 at t==0) ----
    f32x4 acc = {0.f, 0.f, 0.f, 0.f};
    const short* arow = lA + l15*LDS_STRIDE + ksub;
    #pragma unroll
    for (int kk = 0; kk < 16; ++kk)
      acc = __builtin_amdgcn_mfma_f32_16x16x32_bf16(*(const bf16x8*)(arow + kk*32), wf[kk], acc, 0, 0, 0);
    if (t > 0){
      #pragma unroll
      for (int kk = 16; kk < 32; ++kk)
        acc = __builtin_amdgcn_mfma_f32_16x16x32_bf16(*(const bf16x8*)(arow + kk*32), wf[kk], acc, 0, 0, 0);
    }

    // ---- epilogue: bias + tanh; coherent act stores only before the flag ----
    float vv[4];
    #pragma unroll
    for (int r = 0; r < 4; ++r){
      vv[r] = fast_tanh(acc[r] + bsum);   // C/D: col=lane&15, row=lq*4+r (m89-verified)
      int brow = lq*4 + r;
      long srow = (long)(t*NL + i)*BB + bg0 + brow;
      if (usews){
        __hip_atomic_store(actbf + srow*HH + jcol, f2bf(vv[r]),
                           __ATOMIC_RELAXED, __HIP_MEMORY_SCOPE_AGENT);
      } else {
        __hip_atomic_store((uint32_t*)(states + srow*HH + jcol),
                           __builtin_bit_cast(uint32_t, vv[r]),
                           __ATOMIC_RELAXED, __HIP_MEMORY_SCOPE_AGENT);
      }
    }

    // __syncthreads emits s_waitcnt vmcnt(0) before s_barrier: every wave's
    // coherent stores are complete at the agent coherence point before tid0
    // publishes the flag. That IS the release ordering — no fence instruction.
    __syncthreads();
    if (tid == 0)
      __hip_atomic_fetch_add(&flags[FIDX(t, i, m)], 1,
                             __ATOMIC_RELAXED, __HIP_MEMORY_SCOPE_AGENT);

    // ---- deferred f32 result stores: not consumed in-kernel, so they drain
    //      in the shadow of the next step's wait/stage instead of gating it ----
    if (usews){
      #pragma unroll
      for (int r = 0; r < 4; ++r){
        int brow = lq*4 + r;
        long srow = (long)(t*NL + i)*BB + bg0 + brow;
        __builtin_nontemporal_store(vv[r], states + srow*HH + jcol);
      }
    }
    if (i == NL-1){
      #pragma unroll
      for (int r = 0; r < 4; ++r){
        int brow = lq*4 + r;
        __builtin_nontemporal_store(vv[r], out + ((long)t*BB + bg0 + brow)*HH + jcol);
      }
    }
  }
}

extern "C" void kernel_launch(void* const* d_in, const int* in_sizes, int n_in,
                              void* d_out, int out_size, void* d_ws, size_t ws_size,
                              hipStream_t stream)
{
  (void)in_sizes; (void)n_in; (void)out_size;
  const float* x    = (const float*)d_in[0];
  const float* w_ih = (const float*)d_in[1];
  const float* b_ih = (const float*)d_in[2];
  const float* w_hh = (const float*)d_in[3];
  const float* b_hh = (const float*)d_in[4];
  float* out = (float*)d_out;

  // ws layout: [0,256K) flags (64B-padded) | [256K, +16.8M) x_bf16 | acts_bf16 (67.1MB)
  const size_t FLAGS_BYTES = (size_t)SEQ*NL*GM*FLAG_STRIDE*4;  // 256 KB
  const size_t X_OFF     = FLAGS_BYTES;
  const size_t XBF_BYTES = (size_t)SEQ*BB*HH*2;
  const size_t ACT_OFF   = X_OFF + XBF_BYTES;
  const size_t ACT_BYTES = (size_t)SEQ*NL*BB*HH*2;
  int usews = (ws_size >= ACT_OFF + ACT_BYTES) ? 1 : 0;

  int*   flags = (int*)d_ws;
  short* xbf   = (short*)((char*)d_ws + X_OFF);
  short* actbf = (short*)((char*)d_ws + ACT_OFF);

  int prep_blocks = usews ? (1 + SEQ*BB*HH/(WGT*8)) : 1;   // 4097 or 1
  hipLaunchKernelGGL(rnn_prep, dim3(prep_blocks), dim3(WGT), 0, stream,
                     x, xbf, flags, usews);
  hipLaunchKernelGGL(rnn_main, dim3(NL*GM*GN), dim3(TPB), 0, stream,
                     x, w_ih, b_ih, w_hh, b_hh, out, xbf, actbf, flags, usews);
}